// Round 8
// baseline (518.088 us; speedup 1.0000x reference)
//
#include <hip/hip_runtime.h>
#include <hip/hip_bf16.h>
#include <stdint.h>

#define T_ 128
#define B_ 8
#define V_ 32000
#define E_ 128
#define H_ 256
#define N_ 20
#define M_ 1024        // B*T rows
#define PIT 264        // LDS pitch (shorts) for K=256 tiles
#define PIT2 136       // LDS pitch (shorts) for K=128 tiles
#define NCH2 1000      // V/32 stat chunks

typedef __attribute__((ext_vector_type(8))) short short8;
typedef __attribute__((ext_vector_type(4))) float f32x4;
typedef unsigned short ushort;

static __device__ __forceinline__ ushort f2bf_u(float f) {
  __hip_bfloat16 h = __float2bfloat16(f);
  return *reinterpret_cast<ushort*>(&h);
}

// ---------- whT[j][i] = W_h[i][j] ----------
__global__ void whT_k(const float* __restrict__ Wh, float* __restrict__ whT) {
  int idx = blockIdx.x*256 + threadIdx.x;   // 65536
  int i = idx >> 8, j = idx & 255;
  whT[j*H_ + i] = Wh[i*H_ + j];
}

// ---------- WiT[e][i] = W_i[i][e] ----------
__global__ void wit_k(const float* __restrict__ Wi, float* __restrict__ WiT) {
  int idx = blockIdx.x*256 + threadIdx.x;
  if (idx < H_*E_) {
    int i = idx >> 7, e = idx & (E_-1);
    WiT[e*H_ + i] = Wi[idx];
  }
}

// ---------- embnb[v][e] = bf16(emb[v][e]/max(||emb[v]||,1e-8)) ----------
__global__ void embn_k(const float* __restrict__ emb, ushort* __restrict__ embnb) {
  int v = blockIdx.x, l = threadIdx.x;  // 64 threads
  float e0 = emb[v*E_ + l];
  float e1 = emb[v*E_ + 64 + l];
  float ss = e0*e0 + e1*e1;
  #pragma unroll
  for (int off = 32; off >= 1; off >>= 1) ss += __shfl_xor(ss, off);
  float inv = 1.f / fmaxf(sqrtf(ss), 1e-8f);
  embnb[v*E_ + l]      = f2bf_u(e0*inv);
  embnb[v*E_ + 64 + l] = f2bf_u(e1*inv);
}

// ---------- Wfcb[n][k] = bf16(W_fc[n][k] + W_fc[n][256+k]) ----------
__global__ void foldfc_k(const float* __restrict__ Wfc, ushort* __restrict__ Wfcb) {
  int idx = blockIdx.x*256 + threadIdx.x;   // 8,192,000
  int n = idx >> 8, k = idx & 255;
  Wfcb[idx] = f2bf_u(Wfc[n*2*H_ + k] + Wfc[n*2*H_ + H_ + k]);
}

// ---------- RI[r][i] = (l2norm(emb[x_ids]) @ W_i.T)[i] ----------
__global__ __launch_bounds__(256) void ri_k(const int* __restrict__ x_ids,
    const float* __restrict__ emb, const float* __restrict__ WiT,
    float* __restrict__ RI)
{
  __shared__ float xn[E_];
  __shared__ float red[2];
  int r = blockIdx.x, tid = threadIdx.x;
  int id = x_ids[r];
  float v = 0.f;
  if (tid < E_) v = emb[id*E_ + tid];
  float ss = v*v;
  if (tid < E_) {
    #pragma unroll
    for (int off = 32; off >= 1; off >>= 1) ss += __shfl_xor(ss, off);
    if ((tid & 63) == 0) red[tid >> 6] = ss;
  }
  __syncthreads();
  float inv = 1.f / fmaxf(sqrtf(red[0] + red[1]), 1e-12f);
  if (tid < E_) xn[tid] = v*inv;
  __syncthreads();
  float s = 0.f;
  for (int e = 0; e < E_; ++e) s += xn[e]*WiT[e*H_ + tid];
  RI[r*H_ + tid] = s;
}

// ---------- h-chain: 256 thr, W_h row fp32 in 256 VGPRs, ping-pong h, 1 barrier ----------
__global__ __launch_bounds__(256, 1) void chain_k(
    const float* __restrict__ whT, const float* __restrict__ RI,
    float* __restrict__ HMf, ushort* __restrict__ HMb)
{
  __shared__ __align__(16) float hbuf[2][H_];
  const int b = blockIdx.x, i = threadIdx.x;

  float wreg[256];                      // W_h[i][0..256), coalesced via whT[j][i]
  #pragma unroll
  for (int u = 0; u < 256; ++u) wreg[u] = whT[u*H_ + i];

  hbuf[0][i] = 0.f;
  __syncthreads();
  float ri_c = RI[(size_t)b*T_*H_ + i];

  for (int t = 0; t < T_; ++t) {
    const int r = b*T_ + t;
    float ri_n = 0.f;
    if (t+1 < T_) ri_n = RI[(size_t)(r+1)*H_ + i];        // prefetch next step
    const float4* h4 = reinterpret_cast<const float4*>(hbuf[t & 1]);
    float p0 = 0.f, p1 = 0.f, p2 = 0.f, p3 = 0.f;
    #pragma unroll
    for (int u = 0; u < 16; ++u) {
      float4 xa = h4[u*4+0], xb = h4[u*4+1], xc = h4[u*4+2], xd = h4[u*4+3];
      p0 += wreg[u*16+ 0]*xa.x + wreg[u*16+ 1]*xa.y + wreg[u*16+ 2]*xa.z + wreg[u*16+ 3]*xa.w;
      p1 += wreg[u*16+ 4]*xb.x + wreg[u*16+ 5]*xb.y + wreg[u*16+ 6]*xb.z + wreg[u*16+ 7]*xb.w;
      p2 += wreg[u*16+ 8]*xc.x + wreg[u*16+ 9]*xc.y + wreg[u*16+10]*xc.z + wreg[u*16+11]*xc.w;
      p3 += wreg[u*16+12]*xd.x + wreg[u*16+13]*xd.y + wreg[u*16+14]*xd.z + wreg[u*16+15]*xd.w;
    }
    float s = ri_c + (p0 + p1) + (p2 + p3);
    float hn = tanhf(s);
    hbuf[(t+1) & 1][i] = hn;            // other buffer: no WAR with in-flight reads
    float hm = 1.f - fmaxf(hn, 0.f);
    HMf[(size_t)r*H_ + i] = hm;
    HMb[(size_t)r*H_ + i] = f2bf_u(hm);
    ri_c = ri_n;
    __syncthreads();                    // single barrier per step
  }
}

// ---------- per-row gate softmaxes (parallel over all 1024 rows) ----------
__global__ void dots_k(const float* __restrict__ HMf,
    const float* __restrict__ W_ops, const float* __restrict__ W_ch,
    float* __restrict__ OPS, float* __restrict__ CH)
{
  int r = blockIdx.x, l = threadIdx.x;   // 64 threads
  float4 hm4 = reinterpret_cast<const float4*>(HMf + (size_t)r*H_)[l];
  float d[5];
  #pragma unroll
  for (int k = 0; k < 3; ++k) {
    float w0 = W_ops[k*2*H_ + 4*l+0] + W_ops[k*2*H_ + H_ + 4*l+0];
    float w1 = W_ops[k*2*H_ + 4*l+1] + W_ops[k*2*H_ + H_ + 4*l+1];
    float w2 = W_ops[k*2*H_ + 4*l+2] + W_ops[k*2*H_ + H_ + 4*l+2];
    float w3 = W_ops[k*2*H_ + 4*l+3] + W_ops[k*2*H_ + H_ + 4*l+3];
    d[k] = hm4.x*w0 + hm4.y*w1 + hm4.z*w2 + hm4.w*w3;
  }
  #pragma unroll
  for (int k = 0; k < 2; ++k) {
    float w0 = W_ch[k*2*H_ + 4*l+0] + W_ch[k*2*H_ + H_ + 4*l+0];
    float w1 = W_ch[k*2*H_ + 4*l+1] + W_ch[k*2*H_ + H_ + 4*l+1];
    float w2 = W_ch[k*2*H_ + 4*l+2] + W_ch[k*2*H_ + H_ + 4*l+2];
    float w3 = W_ch[k*2*H_ + 4*l+3] + W_ch[k*2*H_ + H_ + 4*l+3];
    d[3+k] = hm4.x*w0 + hm4.y*w1 + hm4.z*w2 + hm4.w*w3;
  }
  #pragma unroll
  for (int off = 32; off >= 1; off >>= 1)
    #pragma unroll
    for (int k = 0; k < 5; ++k) d[k] += __shfl_xor(d[k], off);
  if (l == 0) {
    float mx = fmaxf(d[0], fmaxf(d[1], d[2]));
    float e0 = expf(d[0]-mx), e1 = expf(d[1]-mx), e2 = expf(d[2]-mx);
    float oi = 1.f/(e0+e1+e2);
    OPS[r*4+0] = e0*oi; OPS[r*4+1] = e1*oi; OPS[r*4+2] = e2*oi;
    float cm = fmaxf(d[3], d[4]);
    float f0 = expf(d[3]-cm), f1 = expf(d[4]-cm);
    float ci = 1.f/(f0+f1);
    CH[r*2] = f0*ci; CH[r*2+1] = f1*ci;
  }
}

// ---------- tiny serial ptr recurrence: lane n owns ptr[n] ----------
__global__ __launch_bounds__(64) void ptrw_k(const float* __restrict__ OPS,
    const float* __restrict__ sharp, float2* __restrict__ PTRW)
{
  __shared__ float ops_s[T_*4];
  const int b = blockIdx.x, l = threadIdx.x;
  for (int m = l; m < T_*4; m += 64) ops_s[m] = OPS[(size_t)b*T_*4 + m];
  const float sh = sharp[0];
  float ptr = (l == 0) ? 1.f : 0.f;               // lane l owns ptr[l], l<20
  const int lp = (l + N_ - 1) % N_;
  const int ln = (l + 1) % N_;
  for (int t = 0; t < T_; ++t) {
    float push = ops_s[t*4+0], pop = ops_s[t*4+1], nop = ops_s[t*4+2];
    float pp = __shfl(ptr, lp);
    float po = __shfl(ptr, ln);
    float w = push*pp;
    float raw = w + pop*po + nop*ptr;
    float np = 0.f;
    if (l < N_) np = exp2f(sh * log2f(fmaxf(raw, 1e-8f)));
    float ssum = np;
    #pragma unroll
    for (int off = 1; off < 32; off <<= 1) ssum += __shfl_xor(ssum, off);
    if (l < N_) {
      PTRW[(size_t)(b*T_ + t)*N_ + l] = make_float2(ptr, w);  // carry-in ptr, push weight
      ptr = np / ssum;
    }
  }
}

// ---------- stack evolution + pop_val: thread=(b,e), stck[20] in regs ----------
__global__ __launch_bounds__(128) void pv_k(const int* __restrict__ x_ids,
    const float* __restrict__ emb, const float2* __restrict__ PTRW,
    float* __restrict__ PV)
{
  __shared__ float2 pw_s[T_*N_];                  // 20 KB
  __shared__ int ids_s[T_];
  const int b = blockIdx.x, e = threadIdx.x;
  for (int m = e; m < T_*N_; m += 128) pw_s[m] = PTRW[(size_t)b*T_*N_ + m];
  if (e < T_) ids_s[e] = x_ids[b*T_ + e];
  __syncthreads();
  float stck[N_];
  #pragma unroll
  for (int n = 0; n < N_; ++n) stck[n] = 0.001f;
  float xi_c = emb[(size_t)ids_s[0]*E_ + e];
  for (int t = 0; t < T_; ++t) {
    float xi_n = (t+1 < T_) ? emb[(size_t)ids_s[t+1]*E_ + e] : 0.f;  // prefetch
    float pv = 0.f;
    #pragma unroll
    for (int n = 0; n < N_; ++n) {
      float2 pw = pw_s[t*N_ + n];
      pv += pw.x * stck[n];
      stck[n] += pw.y * (xi_c - stck[n]);        // blend with push weight
    }
    PV[(size_t)(b*T_ + t)*E_ + e] = pv;
    xi_c = xi_n;
  }
}

// ---------- normalize pop_val rows -> bf16 PVNb ----------
__global__ void pvn_k(const float* __restrict__ PV, ushort* __restrict__ PVNb) {
  int r = blockIdx.x, l = threadIdx.x;   // 64 threads
  float a = PV[(size_t)r*E_ + l];
  float c = PV[(size_t)r*E_ + 64 + l];
  float ss = a*a + c*c;
  #pragma unroll
  for (int off = 32; off >= 1; off >>= 1) ss += __shfl_xor(ss, off);
  float inv = 1.f / fmaxf(sqrtf(ss), 1e-8f);
  PVNb[(size_t)r*E_ + l]      = f2bf_u(a*inv);
  PVNb[(size_t)r*E_ + 64 + l] = f2bf_u(c*inv);
}

// ================= MFMA GEMM passes (unchanged) =================
__global__ __launch_bounds__(256) void stats2_k(const ushort* __restrict__ HMb,
    const ushort* __restrict__ Wfcb, float* __restrict__ SS)
{
  __shared__ __align__(16) ushort As[64*PIT];
  __shared__ __align__(16) ushort Bs[64*PIT];
  const int tid = threadIdx.x;
  const int Rb = blockIdx.y*64, Cb = blockIdx.x*64;
  const uint4* srcA = (const uint4*)(HMb  + (size_t)Rb*H_);
  const uint4* srcB = (const uint4*)(Wfcb + (size_t)Cb*H_);
  #pragma unroll
  for (int it = 0; it < 8; ++it) {
    int idx = it*256 + tid, row = idx >> 5, c = idx & 31;
    *(uint4*)&As[row*PIT + c*8] = srcA[row*32 + c];
    *(uint4*)&Bs[row*PIT + c*8] = srcB[row*32 + c];
  }
  __syncthreads();

  const int wave = tid >> 6, lane = tid & 63;
  const int wr = wave >> 1, wc = wave & 1;
  const int lr = lane & 15, g = lane >> 4;
  f32x4 acc[2][2] = {};
  const ushort* Ab = &As[(wr*32 + lr)*PIT + g*8];
  const ushort* Bb = &Bs[(wc*32 + lr)*PIT + g*8];
  #pragma unroll
  for (int ks = 0; ks < 8; ++ks) {
    short8 a0 = *(const short8*)(Ab + ks*32);
    short8 a1 = *(const short8*)(Ab + 16*PIT + ks*32);
    short8 b0 = *(const short8*)(Bb + ks*32);
    short8 b1 = *(const short8*)(Bb + 16*PIT + ks*32);
    acc[0][0] = __builtin_amdgcn_mfma_f32_16x16x32_bf16(a0, b0, acc[0][0], 0, 0, 0);
    acc[0][1] = __builtin_amdgcn_mfma_f32_16x16x32_bf16(a0, b1, acc[0][1], 0, 0, 0);
    acc[1][0] = __builtin_amdgcn_mfma_f32_16x16x32_bf16(a1, b0, acc[1][0], 0, 0, 0);
    acc[1][1] = __builtin_amdgcn_mfma_f32_16x16x32_bf16(a1, b1, acc[1][1], 0, 0, 0);
  }
  const int chunk = blockIdx.x*2 + wc;
  #pragma unroll
  for (int mi = 0; mi < 2; ++mi)
    #pragma unroll
    for (int r = 0; r < 4; ++r) {
      float s = expf(acc[mi][0][r]) + expf(acc[mi][1][r]);
      #pragma unroll
      for (int off = 1; off < 16; off <<= 1) s += __shfl_xor(s, off);
      if (lr == 0) SS[(size_t)(Rb + wr*32 + mi*16 + g*4 + r)*NCH2 + chunk] = s;
    }
}

__global__ void reduce2_k(const float* __restrict__ SS, float* __restrict__ MS) {
  int row = blockIdx.x, l = threadIdx.x;  // 64 threads
  float s = 0.f;
  for (int c = l; c < NCH2; c += 64) s += SS[(size_t)row*NCH2 + c];
  #pragma unroll
  for (int off = 32; off >= 1; off >>= 1) s += __shfl_xor(s, off);
  if (l == 0) MS[row] = 1.f/s;
}

__global__ __launch_bounds__(256) void final2_k(const ushort* __restrict__ HMb,
    const ushort* __restrict__ Wfcb, const ushort* __restrict__ PVNb,
    const ushort* __restrict__ embnb, const float* __restrict__ MS,
    const float* __restrict__ CH, float* __restrict__ out)
{
  __shared__ __align__(16) ushort As[64*PIT];
  __shared__ __align__(16) ushort Bs[64*PIT];
  const int tid = threadIdx.x;
  const int Rb = blockIdx.y*64, Cb = blockIdx.x*64;
  const int wave = tid >> 6, lane = tid & 63;
  const int wr = wave >> 1, wc = wave & 1;
  const int lr = lane & 15, g = lane >> 4;

  {
    const uint4* srcA = (const uint4*)(HMb  + (size_t)Rb*H_);
    const uint4* srcB = (const uint4*)(Wfcb + (size_t)Cb*H_);
    #pragma unroll
    for (int it = 0; it < 8; ++it) {
      int idx = it*256 + tid, row = idx >> 5, c = idx & 31;
      *(uint4*)&As[row*PIT + c*8] = srcA[row*32 + c];
      *(uint4*)&Bs[row*PIT + c*8] = srcB[row*32 + c];
    }
  }
  __syncthreads();
  f32x4 accL[2][2] = {};
  {
    const ushort* Ab = &As[(wr*32 + lr)*PIT + g*8];
    const ushort* Bb = &Bs[(wc*32 + lr)*PIT + g*8];
    #pragma unroll
    for (int ks = 0; ks < 8; ++ks) {
      short8 a0 = *(const short8*)(Ab + ks*32);
      short8 a1 = *(const short8*)(Ab + 16*PIT + ks*32);
      short8 b0 = *(const short8*)(Bb + ks*32);
      short8 b1 = *(const short8*)(Bb + 16*PIT + ks*32);
      accL[0][0] = __builtin_amdgcn_mfma_f32_16x16x32_bf16(a0, b0, accL[0][0], 0, 0, 0);
      accL[0][1] = __builtin_amdgcn_mfma_f32_16x16x32_bf16(a0, b1, accL[0][1], 0, 0, 0);
      accL[1][0] = __builtin_amdgcn_mfma_f32_16x16x32_bf16(a1, b0, accL[1][0], 0, 0, 0);
      accL[1][1] = __builtin_amdgcn_mfma_f32_16x16x32_bf16(a1, b1, accL[1][1], 0, 0, 0);
    }
  }
  __syncthreads();

  {
    const uint4* srcA = (const uint4*)(PVNb  + (size_t)Rb*E_);
    const uint4* srcB = (const uint4*)(embnb + (size_t)Cb*E_);
    #pragma unroll
    for (int it = 0; it < 4; ++it) {
      int idx = it*256 + tid, row = idx >> 4, c = idx & 15;
      *(uint4*)&As[row*PIT2 + c*8] = srcA[row*16 + c];
      *(uint4*)&Bs[row*PIT2 + c*8] = srcB[row*16 + c];
    }
  }
  __syncthreads();
  f32x4 accS[2][2] = {};
  {
    const ushort* Ab = &As[(wr*32 + lr)*PIT2 + g*8];
    const ushort* Bb = &Bs[(wc*32 + lr)*PIT2 + g*8];
    #pragma unroll
    for (int ks = 0; ks < 4; ++ks) {
      short8 a0 = *(const short8*)(Ab + ks*32);
      short8 a1 = *(const short8*)(Ab + 16*PIT2 + ks*32);
      short8 b0 = *(const short8*)(Bb + ks*32);
      short8 b1 = *(const short8*)(Bb + 16*PIT2 + ks*32);
      accS[0][0] = __builtin_amdgcn_mfma_f32_16x16x32_bf16(a0, b0, accS[0][0], 0, 0, 0);
      accS[0][1] = __builtin_amdgcn_mfma_f32_16x16x32_bf16(a0, b1, accS[0][1], 0, 0, 0);
      accS[1][0] = __builtin_amdgcn_mfma_f32_16x16x32_bf16(a1, b0, accS[1][0], 0, 0, 0);
      accS[1][1] = __builtin_amdgcn_mfma_f32_16x16x32_bf16(a1, b1, accS[1][1], 0, 0, 0);
    }
  }

  #pragma unroll
  for (int mi = 0; mi < 2; ++mi)
    #pragma unroll
    for (int r = 0; r < 4; ++r) {
      int row = Rb + wr*32 + mi*16 + g*4 + r;
      float Si = MS[row];
      float c0 = CH[row*2], c1 = CH[row*2+1];
      float v0 = c0*expf(accL[mi][0][r])*Si + c1*accS[mi][0][r];
      float v1 = c0*expf(accL[mi][1][r])*Si + c1*accS[mi][1][r];
      size_t base = (size_t)row*V_ + Cb + wc*32 + lr;
      out[base]      = v0;
      out[base + 16] = v1;
    }
}

extern "C" void kernel_launch(void* const* d_in, const int* in_sizes, int n_in,
                              void* d_out, int out_size, void* d_ws, size_t ws_size,
                              hipStream_t stream) {
  const int*   x_ids = (const int*)d_in[0];
  const float* emb   = (const float*)d_in[1];
  const float* W_i   = (const float*)d_in[2];
  const float* W_h   = (const float*)d_in[3];
  const float* W_fc  = (const float*)d_in[4];
  const float* W_ops = (const float*)d_in[5];
  const float* W_ch  = (const float*)d_in[6];
  const float* sharp = (const float*)d_in[7];
  float* out = (float*)d_out;

  float* ws    = (float*)d_ws;             // ~33 MB total
  float*  whT  = ws;                       // 65536
  float*  WiT  = whT + 65536;              // 32768
  float*  RI   = WiT + 32768;              // 262144
  float*  CH   = RI + 262144;              // 2048
  float*  MS   = CH + 2048;                // 1024
  float*  SS   = MS + 1024;                // 1,024,000
  float*  HMf  = SS + 1024000;             // 262144
  float*  OPS  = HMf + 262144;             // 4096
  float*  PV   = OPS + 4096;               // 131072
  float2* PTRW = (float2*)(PV + 131072);   // 20480 float2
  float*  fend = PV + 131072 + 40960;
  ushort* HMb   = (ushort*)fend;           // 262144 shorts
  ushort* PVNb  = HMb + 262144;            // 131072
  ushort* Wfcb  = PVNb + 131072;           // 8,192,000
  ushort* embnb = Wfcb + 8192000;          // 4,096,000

  whT_k  <<<H_*H_/256, 256, 0, stream>>>(W_h, whT);
  wit_k  <<<(H_*E_ + 255)/256, 256, 0, stream>>>(W_i, WiT);
  embn_k <<<V_, 64, 0, stream>>>(emb, embnb);
  foldfc_k<<<V_*H_/256, 256, 0, stream>>>(W_fc, Wfcb);
  ri_k   <<<M_, 256, 0, stream>>>(x_ids, emb, WiT, RI);
  chain_k<<<B_, 256, 0, stream>>>(whT, RI, HMf, HMb);
  dots_k <<<M_, 64, 0, stream>>>(HMf, W_ops, W_ch, OPS, CH);
  ptrw_k <<<B_, 64, 0, stream>>>(OPS, sharp, PTRW);
  pv_k   <<<B_, 128, 0, stream>>>(x_ids, emb, PTRW, PV);
  pvn_k  <<<M_, 64, 0, stream>>>(PV, PVNb);
  stats2_k<<<dim3(V_/64, M_/64), 256, 0, stream>>>(HMb, Wfcb, SS);
  reduce2_k<<<M_, 64, 0, stream>>>(SS, MS);
  final2_k<<<dim3(V_/64, M_/64), 256, 0, stream>>>(HMb, Wfcb, PVNb, embnb, MS, CH, out);
}

// Round 9
// 437.327 us; speedup vs baseline: 1.1847x; 1.1847x over previous
//
#include <hip/hip_runtime.h>
#include <hip/hip_bf16.h>
#include <stdint.h>

#define T_ 128
#define B_ 8
#define V_ 32000
#define E_ 128
#define H_ 256
#define N_ 20
#define M_ 1024        // B*T rows
#define PIT 264        // LDS pitch (shorts) for K=256 tiles
#define PIT2 136       // LDS pitch (shorts) for K=128 tiles
#define NCH2 1000      // V/32 stat chunks

typedef __attribute__((ext_vector_type(8))) short short8;
typedef __attribute__((ext_vector_type(4))) float f32x4;
typedef unsigned short ushort;

static __device__ __forceinline__ ushort f2bf_u(float f) {
  __hip_bfloat16 h = __float2bfloat16(f);
  return *reinterpret_cast<ushort*>(&h);
}

// ---------- whb4[k8*256 + i] = bf16x8 of W_h[i][k8*8 .. k8*8+7] ----------
__global__ void whb_k(const float* __restrict__ Wh, uint4* __restrict__ whb4) {
  int idx = blockIdx.x*256 + threadIdx.x;   // 8192 entries
  int k8 = idx >> 8, i = idx & 255;
  const float* s = Wh + i*H_ + k8*8;
  uint4 o;
  o.x = (uint32_t)f2bf_u(s[0]) | ((uint32_t)f2bf_u(s[1]) << 16);
  o.y = (uint32_t)f2bf_u(s[2]) | ((uint32_t)f2bf_u(s[3]) << 16);
  o.z = (uint32_t)f2bf_u(s[4]) | ((uint32_t)f2bf_u(s[5]) << 16);
  o.w = (uint32_t)f2bf_u(s[6]) | ((uint32_t)f2bf_u(s[7]) << 16);
  whb4[idx] = o;
}

// ---------- WiT[e][i] = W_i[i][e] ----------
__global__ void wit_k(const float* __restrict__ Wi, float* __restrict__ WiT) {
  int idx = blockIdx.x*256 + threadIdx.x;
  if (idx < H_*E_) {
    int i = idx >> 7, e = idx & (E_-1);
    WiT[e*H_ + i] = Wi[idx];
  }
}

// ---------- embnb[v][e] = bf16(emb[v][e]/max(||emb[v]||,1e-8)) ----------
__global__ void embn_k(const float* __restrict__ emb, ushort* __restrict__ embnb) {
  int v = blockIdx.x, l = threadIdx.x;  // 64 threads
  float e0 = emb[v*E_ + l];
  float e1 = emb[v*E_ + 64 + l];
  float ss = e0*e0 + e1*e1;
  #pragma unroll
  for (int off = 32; off >= 1; off >>= 1) ss += __shfl_xor(ss, off);
  float inv = 1.f / fmaxf(sqrtf(ss), 1e-8f);
  embnb[v*E_ + l]      = f2bf_u(e0*inv);
  embnb[v*E_ + 64 + l] = f2bf_u(e1*inv);
}

// ---------- Wfcb[n][k] = bf16(W_fc[n][k] + W_fc[n][256+k]) ----------
__global__ void foldfc_k(const float* __restrict__ Wfc, ushort* __restrict__ Wfcb) {
  int idx = blockIdx.x*256 + threadIdx.x;   // 8,192,000
  int n = idx >> 8, k = idx & 255;
  Wfcb[idx] = f2bf_u(Wfc[n*2*H_ + k] + Wfc[n*2*H_ + H_ + k]);
}

// ---------- RI[r][i] = (l2norm(emb[x_ids]) @ W_i.T)[i] ----------
__global__ __launch_bounds__(256) void ri_k(const int* __restrict__ x_ids,
    const float* __restrict__ emb, const float* __restrict__ WiT,
    float* __restrict__ RI)
{
  __shared__ float xn[E_];
  __shared__ float red[2];
  int r = blockIdx.x, tid = threadIdx.x;
  int id = x_ids[r];
  float v = 0.f;
  if (tid < E_) v = emb[id*E_ + tid];
  float ss = v*v;
  if (tid < E_) {
    #pragma unroll
    for (int off = 32; off >= 1; off >>= 1) ss += __shfl_xor(ss, off);
    if ((tid & 63) == 0) red[tid >> 6] = ss;
  }
  __syncthreads();
  float inv = 1.f / fmaxf(sqrtf(red[0] + red[1]), 1e-12f);
  if (tid < E_) xn[tid] = v*inv;
  __syncthreads();
  float s = 0.f;
  for (int e = 0; e < E_; ++e) s += xn[e]*WiT[e*H_ + tid];
  RI[r*H_ + tid] = s;
}

// ---------- h-chain: W_h bf16 in LDS (128KB), 1024 thr, fp32 h ----------
// thread (q,i): q=tid>>8 covers k in [q*64,(q+1)*64) of output row i.
__global__ __launch_bounds__(1024) void chain_k(
    const uint4* __restrict__ whb4, const float* __restrict__ RI,
    float* __restrict__ HMf, ushort* __restrict__ HMb)
{
  __shared__ uint4 wlds[32*256];                  // 128 KB, [k8][i]
  __shared__ __align__(16) float hbuf[2][H_];
  __shared__ float hred[3][H_];
  const int b = blockIdx.x, tid = threadIdx.x;
  const int q = tid >> 8, i = tid & 255;

  for (int m = tid; m < 32*256; m += 1024) wlds[m] = whb4[m];
  if (q == 0) hbuf[0][i] = 0.f;
  __syncthreads();
  float ri_c = (q == 0) ? RI[(size_t)b*T_*H_ + i] : 0.f;

  for (int t = 0; t < T_; ++t) {
    const int r = b*T_ + t;
    float ri_n = 0.f;
    if (q == 0 && t+1 < T_) ri_n = RI[(size_t)(r+1)*H_ + i];  // prefetch
    const float4* h4 = reinterpret_cast<const float4*>(hbuf[t & 1]);
    float p0 = 0.f, p1 = 0.f, p2 = 0.f, p3 = 0.f;
    #pragma unroll
    for (int j = 0; j < 8; ++j) {
      uint4 w = wlds[(q*8 + j)*256 + i];          // lane-contiguous b128
      float4 ha = h4[q*16 + 2*j];                 // wave-uniform broadcast
      float4 hb = h4[q*16 + 2*j + 1];
      p0 += __uint_as_float(w.x << 16)*ha.x + __uint_as_float(w.x & 0xffff0000u)*ha.y;
      p1 += __uint_as_float(w.y << 16)*ha.z + __uint_as_float(w.y & 0xffff0000u)*ha.w;
      p2 += __uint_as_float(w.z << 16)*hb.x + __uint_as_float(w.z & 0xffff0000u)*hb.y;
      p3 += __uint_as_float(w.w << 16)*hb.z + __uint_as_float(w.w & 0xffff0000u)*hb.w;
    }
    float p = (p0 + p1) + (p2 + p3);
    if (q) hred[q-1][i] = p;
    __syncthreads();
    if (q == 0) {
      float s = ri_c + p + hred[0][i] + hred[1][i] + hred[2][i];
      float hn = tanhf(s);
      hbuf[(t+1) & 1][i] = hn;                    // ping-pong: no WAR
      float hm = 1.f - fmaxf(hn, 0.f);
      HMf[(size_t)r*H_ + i] = hm;
      HMb[(size_t)r*H_ + i] = f2bf_u(hm);
    }
    ri_c = ri_n;
    __syncthreads();
  }
}

// ---------- per-row gate softmaxes (parallel over all 1024 rows) ----------
__global__ void dots_k(const float* __restrict__ HMf,
    const float* __restrict__ W_ops, const float* __restrict__ W_ch,
    float* __restrict__ OPS, float* __restrict__ CH)
{
  int r = blockIdx.x, l = threadIdx.x;   // 64 threads
  float4 hm4 = reinterpret_cast<const float4*>(HMf + (size_t)r*H_)[l];
  float d[5];
  #pragma unroll
  for (int k = 0; k < 3; ++k) {
    float w0 = W_ops[k*2*H_ + 4*l+0] + W_ops[k*2*H_ + H_ + 4*l+0];
    float w1 = W_ops[k*2*H_ + 4*l+1] + W_ops[k*2*H_ + H_ + 4*l+1];
    float w2 = W_ops[k*2*H_ + 4*l+2] + W_ops[k*2*H_ + H_ + 4*l+2];
    float w3 = W_ops[k*2*H_ + 4*l+3] + W_ops[k*2*H_ + H_ + 4*l+3];
    d[k] = hm4.x*w0 + hm4.y*w1 + hm4.z*w2 + hm4.w*w3;
  }
  #pragma unroll
  for (int k = 0; k < 2; ++k) {
    float w0 = W_ch[k*2*H_ + 4*l+0] + W_ch[k*2*H_ + H_ + 4*l+0];
    float w1 = W_ch[k*2*H_ + 4*l+1] + W_ch[k*2*H_ + H_ + 4*l+1];
    float w2 = W_ch[k*2*H_ + 4*l+2] + W_ch[k*2*H_ + H_ + 4*l+2];
    float w3 = W_ch[k*2*H_ + 4*l+3] + W_ch[k*2*H_ + H_ + 4*l+3];
    d[3+k] = hm4.x*w0 + hm4.y*w1 + hm4.z*w2 + hm4.w*w3;
  }
  #pragma unroll
  for (int off = 32; off >= 1; off >>= 1)
    #pragma unroll
    for (int k = 0; k < 5; ++k) d[k] += __shfl_xor(d[k], off);
  if (l == 0) {
    float mx = fmaxf(d[0], fmaxf(d[1], d[2]));
    float e0 = expf(d[0]-mx), e1 = expf(d[1]-mx), e2 = expf(d[2]-mx);
    float oi = 1.f/(e0+e1+e2);
    OPS[r*4+0] = e0*oi; OPS[r*4+1] = e1*oi; OPS[r*4+2] = e2*oi;
    float cm = fmaxf(d[3], d[4]);
    float f0 = expf(d[3]-cm), f1 = expf(d[4]-cm);
    float ci = 1.f/(f0+f1);
    CH[r*2] = f0*ci; CH[r*2+1] = f1*ci;
  }
}

// ---------- tiny serial ptr recurrence: lane n owns ptr[n] ----------
__global__ __launch_bounds__(64) void ptrw_k(const float* __restrict__ OPS,
    const float* __restrict__ sharp, float2* __restrict__ PTRW)
{
  __shared__ float ops_s[T_*4];
  const int b = blockIdx.x, l = threadIdx.x;
  for (int m = l; m < T_*4; m += 64) ops_s[m] = OPS[(size_t)b*T_*4 + m];
  const float sh = sharp[0];
  float ptr = (l == 0) ? 1.f : 0.f;               // lane l owns ptr[l], l<20
  const int lp = (l + N_ - 1) % N_;
  const int ln = (l + 1) % N_;
  for (int t = 0; t < T_; ++t) {
    float push = ops_s[t*4+0], pop = ops_s[t*4+1], nop = ops_s[t*4+2];
    float pp = __shfl(ptr, lp);
    float po = __shfl(ptr, ln);
    float w = push*pp;
    float raw = w + pop*po + nop*ptr;
    float np = 0.f;
    if (l < N_) np = exp2f(sh * log2f(fmaxf(raw, 1e-8f)));
    float ssum = np;
    #pragma unroll
    for (int off = 1; off < 32; off <<= 1) ssum += __shfl_xor(ssum, off);
    if (l < N_) {
      PTRW[(size_t)(b*T_ + t)*N_ + l] = make_float2(ptr, w);  // carry-in ptr, push weight
      ptr = np / ssum;
    }
  }
}

// ---------- stack evolution + pop_val: thread=(b,e), stck[20] in regs ----------
__global__ __launch_bounds__(128) void pv_k(const int* __restrict__ x_ids,
    const float* __restrict__ emb, const float2* __restrict__ PTRW,
    float* __restrict__ PV)
{
  __shared__ float2 pw_s[T_*N_];                  // 20 KB
  __shared__ int ids_s[T_];
  const int b = blockIdx.x, e = threadIdx.x;
  for (int m = e; m < T_*N_; m += 128) pw_s[m] = PTRW[(size_t)b*T_*N_ + m];
  if (e < T_) ids_s[e] = x_ids[b*T_ + e];
  __syncthreads();
  float stck[N_];
  #pragma unroll
  for (int n = 0; n < N_; ++n) stck[n] = 0.001f;
  float xi_c = emb[(size_t)ids_s[0]*E_ + e];
  for (int t = 0; t < T_; ++t) {
    float xi_n = (t+1 < T_) ? emb[(size_t)ids_s[t+1]*E_ + e] : 0.f;  // prefetch
    float pv = 0.f;
    #pragma unroll
    for (int n = 0; n < N_; ++n) {
      float2 pw = pw_s[t*N_ + n];
      pv += pw.x * stck[n];
      stck[n] += pw.y * (xi_c - stck[n]);        // blend with push weight
    }
    PV[(size_t)(b*T_ + t)*E_ + e] = pv;
    xi_c = xi_n;
  }
}

// ---------- normalize pop_val rows -> bf16 PVNb ----------
__global__ void pvn_k(const float* __restrict__ PV, ushort* __restrict__ PVNb) {
  int r = blockIdx.x, l = threadIdx.x;   // 64 threads
  float a = PV[(size_t)r*E_ + l];
  float c = PV[(size_t)r*E_ + 64 + l];
  float ss = a*a + c*c;
  #pragma unroll
  for (int off = 32; off >= 1; off >>= 1) ss += __shfl_xor(ss, off);
  float inv = 1.f / fmaxf(sqrtf(ss), 1e-8f);
  PVNb[(size_t)r*E_ + l]      = f2bf_u(a*inv);
  PVNb[(size_t)r*E_ + 64 + l] = f2bf_u(c*inv);
}

// ================= MFMA GEMM passes (unchanged) =================
__global__ __launch_bounds__(256) void stats2_k(const ushort* __restrict__ HMb,
    const ushort* __restrict__ Wfcb, float* __restrict__ SS)
{
  __shared__ __align__(16) ushort As[64*PIT];
  __shared__ __align__(16) ushort Bs[64*PIT];
  const int tid = threadIdx.x;
  const int Rb = blockIdx.y*64, Cb = blockIdx.x*64;
  const uint4* srcA = (const uint4*)(HMb  + (size_t)Rb*H_);
  const uint4* srcB = (const uint4*)(Wfcb + (size_t)Cb*H_);
  #pragma unroll
  for (int it = 0; it < 8; ++it) {
    int idx = it*256 + tid, row = idx >> 5, c = idx & 31;
    *(uint4*)&As[row*PIT + c*8] = srcA[row*32 + c];
    *(uint4*)&Bs[row*PIT + c*8] = srcB[row*32 + c];
  }
  __syncthreads();

  const int wave = tid >> 6, lane = tid & 63;
  const int wr = wave >> 1, wc = wave & 1;
  const int lr = lane & 15, g = lane >> 4;
  f32x4 acc[2][2] = {};
  const ushort* Ab = &As[(wr*32 + lr)*PIT + g*8];
  const ushort* Bb = &Bs[(wc*32 + lr)*PIT + g*8];
  #pragma unroll
  for (int ks = 0; ks < 8; ++ks) {
    short8 a0 = *(const short8*)(Ab + ks*32);
    short8 a1 = *(const short8*)(Ab + 16*PIT + ks*32);
    short8 b0 = *(const short8*)(Bb + ks*32);
    short8 b1 = *(const short8*)(Bb + 16*PIT + ks*32);
    acc[0][0] = __builtin_amdgcn_mfma_f32_16x16x32_bf16(a0, b0, acc[0][0], 0, 0, 0);
    acc[0][1] = __builtin_amdgcn_mfma_f32_16x16x32_bf16(a0, b1, acc[0][1], 0, 0, 0);
    acc[1][0] = __builtin_amdgcn_mfma_f32_16x16x32_bf16(a1, b0, acc[1][0], 0, 0, 0);
    acc[1][1] = __builtin_amdgcn_mfma_f32_16x16x32_bf16(a1, b1, acc[1][1], 0, 0, 0);
  }
  const int chunk = blockIdx.x*2 + wc;
  #pragma unroll
  for (int mi = 0; mi < 2; ++mi)
    #pragma unroll
    for (int r = 0; r < 4; ++r) {
      float s = expf(acc[mi][0][r]) + expf(acc[mi][1][r]);
      #pragma unroll
      for (int off = 1; off < 16; off <<= 1) s += __shfl_xor(s, off);
      if (lr == 0) SS[(size_t)(Rb + wr*32 + mi*16 + g*4 + r)*NCH2 + chunk] = s;
    }
}

__global__ void reduce2_k(const float* __restrict__ SS, float* __restrict__ MS) {
  int row = blockIdx.x, l = threadIdx.x;  // 64 threads
  float s = 0.f;
  for (int c = l; c < NCH2; c += 64) s += SS[(size_t)row*NCH2 + c];
  #pragma unroll
  for (int off = 32; off >= 1; off >>= 1) s += __shfl_xor(s, off);
  if (l == 0) MS[row] = 1.f/s;
}

__global__ __launch_bounds__(256) void final2_k(const ushort* __restrict__ HMb,
    const ushort* __restrict__ Wfcb, const ushort* __restrict__ PVNb,
    const ushort* __restrict__ embnb, const float* __restrict__ MS,
    const float* __restrict__ CH, float* __restrict__ out)
{
  __shared__ __align__(16) ushort As[64*PIT];
  __shared__ __align__(16) ushort Bs[64*PIT];
  const int tid = threadIdx.x;
  const int Rb = blockIdx.y*64, Cb = blockIdx.x*64;
  const int wave = tid >> 6, lane = tid & 63;
  const int wr = wave >> 1, wc = wave & 1;
  const int lr = lane & 15, g = lane >> 4;

  {
    const uint4* srcA = (const uint4*)(HMb  + (size_t)Rb*H_);
    const uint4* srcB = (const uint4*)(Wfcb + (size_t)Cb*H_);
    #pragma unroll
    for (int it = 0; it < 8; ++it) {
      int idx = it*256 + tid, row = idx >> 5, c = idx & 31;
      *(uint4*)&As[row*PIT + c*8] = srcA[row*32 + c];
      *(uint4*)&Bs[row*PIT + c*8] = srcB[row*32 + c];
    }
  }
  __syncthreads();
  f32x4 accL[2][2] = {};
  {
    const ushort* Ab = &As[(wr*32 + lr)*PIT + g*8];
    const ushort* Bb = &Bs[(wc*32 + lr)*PIT + g*8];
    #pragma unroll
    for (int ks = 0; ks < 8; ++ks) {
      short8 a0 = *(const short8*)(Ab + ks*32);
      short8 a1 = *(const short8*)(Ab + 16*PIT + ks*32);
      short8 b0 = *(const short8*)(Bb + ks*32);
      short8 b1 = *(const short8*)(Bb + 16*PIT + ks*32);
      accL[0][0] = __builtin_amdgcn_mfma_f32_16x16x32_bf16(a0, b0, accL[0][0], 0, 0, 0);
      accL[0][1] = __builtin_amdgcn_mfma_f32_16x16x32_bf16(a0, b1, accL[0][1], 0, 0, 0);
      accL[1][0] = __builtin_amdgcn_mfma_f32_16x16x32_bf16(a1, b0, accL[1][0], 0, 0, 0);
      accL[1][1] = __builtin_amdgcn_mfma_f32_16x16x32_bf16(a1, b1, accL[1][1], 0, 0, 0);
    }
  }
  __syncthreads();

  {
    const uint4* srcA = (const uint4*)(PVNb  + (size_t)Rb*E_);
    const uint4* srcB = (const uint4*)(embnb + (size_t)Cb*E_);
    #pragma unroll
    for (int it = 0; it < 4; ++it) {
      int idx = it*256 + tid, row = idx >> 4, c = idx & 15;
      *(uint4*)&As[row*PIT2 + c*8] = srcA[row*16 + c];
      *(uint4*)&Bs[row*PIT2 + c*8] = srcB[row*16 + c];
    }
  }
  __syncthreads();
  f32x4 accS[2][2] = {};
  {
    const ushort* Ab = &As[(wr*32 + lr)*PIT2 + g*8];
    const ushort* Bb = &Bs[(wc*32 + lr)*PIT2 + g*8];
    #pragma unroll
    for (int ks = 0; ks < 4; ++ks) {
      short8 a0 = *(const short8*)(Ab + ks*32);
      short8 a1 = *(const short8*)(Ab + 16*PIT2 + ks*32);
      short8 b0 = *(const short8*)(Bb + ks*32);
      short8 b1 = *(const short8*)(Bb + 16*PIT2 + ks*32);
      accS[0][0] = __builtin_amdgcn_mfma_f32_16x16x32_bf16(a0, b0, accS[0][0], 0, 0, 0);
      accS[0][1] = __builtin_amdgcn_mfma_f32_16x16x32_bf16(a0, b1, accS[0][1], 0, 0, 0);
      accS[1][0] = __builtin_amdgcn_mfma_f32_16x16x32_bf16(a1, b0, accS[1][0], 0, 0, 0);
      accS[1][1] = __builtin_amdgcn_mfma_f32_16x16x32_bf16(a1, b1, accS[1][1], 0, 0, 0);
    }
  }

  #pragma unroll
  for (int mi = 0; mi < 2; ++mi)
    #pragma unroll
    for (int r = 0; r < 4; ++r) {
      int row = Rb + wr*32 + mi*16 + g*4 + r;
      float Si = MS[row];
      float c0 = CH[row*2], c1 = CH[row*2+1];
      float v0 = c0*expf(accL[mi][0][r])*Si + c1*accS[mi][0][r];
      float v1 = c0*expf(accL[mi][1][r])*Si + c1*accS[mi][1][r];
      size_t base = (size_t)row*V_ + Cb + wc*32 + lr;
      out[base]      = v0;
      out[base + 16] = v1;
    }
}

extern "C" void kernel_launch(void* const* d_in, const int* in_sizes, int n_in,
                              void* d_out, int out_size, void* d_ws, size_t ws_size,
                              hipStream_t stream) {
  const int*   x_ids = (const int*)d_in[0];
  const float* emb   = (const float*)d_in[1];
  const float* W_i   = (const float*)d_in[2];
  const float* W_h   = (const float*)d_in[3];
  const float* W_fc  = (const float*)d_in[4];
  const float* W_ops = (const float*)d_in[5];
  const float* W_ch  = (const float*)d_in[6];
  const float* sharp = (const float*)d_in[7];
  float* out = (float*)d_out;

  float* ws    = (float*)d_ws;             // ~33 MB total
  uint4*  whb4 = (uint4*)ws;               // 8192 uint4 = 32768 floats
  float*  WiT  = ws + 65536;               // 32768
  float*  RI   = WiT + 32768;              // 262144
  float*  CH   = RI + 262144;              // 2048
  float*  MS   = CH + 2048;                // 1024
  float*  SS   = MS + 1024;                // 1,024,000
  float*  HMf  = SS + 1024000;             // 262144
  float*  OPS  = HMf + 262144;             // 4096
  float*  PV   = OPS + 4096;               // 131072
  float2* PTRW = (float2*)(PV + 131072);   // 20480 float2
  float*  fend = PV + 131072 + 40960;
  ushort* HMb   = (ushort*)fend;           // 262144 shorts
  ushort* PVNb  = HMb + 262144;            // 131072
  ushort* Wfcb  = PVNb + 131072;           // 8,192,000
  ushort* embnb = Wfcb + 8192000;          // 4,096,000

  whb_k  <<<32, 256, 0, stream>>>(W_h, whb4);
  wit_k  <<<(H_*E_ + 255)/256, 256, 0, stream>>>(W_i, WiT);
  embn_k <<<V_, 64, 0, stream>>>(emb, embnb);
  foldfc_k<<<V_*H_/256, 256, 0, stream>>>(W_fc, Wfcb);
  ri_k   <<<M_, 256, 0, stream>>>(x_ids, emb, WiT, RI);
  chain_k<<<B_, 1024, 0, stream>>>(whb4, RI, HMf, HMb);
  dots_k <<<M_, 64, 0, stream>>>(HMf, W_ops, W_ch, OPS, CH);
  ptrw_k <<<B_, 64, 0, stream>>>(OPS, sharp, PTRW);
  pv_k   <<<B_, 128, 0, stream>>>(x_ids, emb, PTRW, PV);
  pvn_k  <<<M_, 64, 0, stream>>>(PV, PVNb);
  stats2_k<<<dim3(V_/64, M_/64), 256, 0, stream>>>(HMb, Wfcb, SS);
  reduce2_k<<<M_, 64, 0, stream>>>(SS, MS);
  final2_k<<<dim3(V_/64, M_/64), 256, 0, stream>>>(HMb, Wfcb, PVNb, embnb, MS, CH, out);
}